// Round 1
// baseline (174.802 us; speedup 1.0000x reference)
//
#include <hip/hip_runtime.h>
#include <math.h>

// ColumnBlockAttention via bf16 MFMA: b=16, t=8192, e=64, BLOCK=64, n_cols=128
// d_out = [out: b*t*64 f32 | A: b*t*128 f32].
//
// One workgroup per (batch, group of MPG=4 m-blocks). Kc/VcT staged ONCE.
// SWAPPED-OPERAND scheme (A/B frag lane maps are symmetric, so swapping is free):
//   GEMM1: Z^T = mfma(Kc_frag, Q_frag)  -> each lane owns ONE query row
//          (row = 16*wid + (lane&15), cols 16t + 4g + reg, g = lane>>4)
//   softmax: per-lane 32-value sum + 2 shuffles (xor 16, 32); nv lane-constant
//   A store: 8 x float4 (cols contiguous per lane)       [was 32 scalar dwords]
//   Aw->LDS: 8 x ds_write_b64 bf16                       [was 32 ds_write_b16]
//   GEMM2: out^T = mfma(VcT_frag, Aw_frag); Out: 4 x float4 [was 16 dwords]
// Aw rows [16wid,16wid+16) are written AND read only by wave wid ->
// NO __syncthreads in the loop; a wave-local s_waitcnt lgkmcnt(0) replaces
// both barriers (each barrier cost a full vmcnt(0) drain of ~50 stores).
// Layouts (HW-verified m89/m120): A[m=lane&15][k=(lane>>4)*8+j],
// B[k][n]: n=lane&15, k=(lane>>4)*8+j; C/D: col=lane&15, row=(lane>>4)*4+reg.

#define TSEQ 8192
#define EDIM 64
#define NCOL 128
#define NBATCH 16
#define MPG 4            // m-blocks per workgroup

typedef __attribute__((ext_vector_type(8))) short short8;
typedef __attribute__((ext_vector_type(4))) short short4v;
typedef __attribute__((ext_vector_type(4))) float f32x4;

__device__ __forceinline__ unsigned short f2bf(float f) {   // RTNE bf16
    unsigned int u = __float_as_uint(f);
    return (unsigned short)((u + 0x7fffu + ((u >> 16) & 1u)) >> 16);
}

__global__ __launch_bounds__(256, 2)
void cba_kernel(const float* __restrict__ Q,
                const float* __restrict__ K,
                const float* __restrict__ V,
                float* __restrict__ Out,
                float* __restrict__ A)
{
    __shared__ unsigned short Kc[NCOL][72];    // Kc[col][dim]   (18432 B)
    __shared__ unsigned short VcT[EDIM][136];  // VcT[dim][col]  (17408 B)
    __shared__ unsigned short Aw[64][136];     // weights [row][col] (17408 B)

    const int tid  = threadIdx.x;
    const int lane = tid & 63;
    const int wid  = tid >> 6;                 // 0..3: rows [16w,16w+16)
    const int b    = blockIdx.x >> 5;          // 0..15
    const int mg   = blockIdx.x & 31;          // m-group: m = 4*mg + it

    const int c   = lane & 15;                 // m/n fragment index
    const int g   = lane >> 4;                 // k-group / col sub-block
    const int kq  = g << 3;                    // 8-dim k-group base
    const int cb  = g << 2;                    // 4-col sub-block base
    const int r   = (wid << 4) + c;            // this lane's query row (in 64)

    // ---- prefetch Q for iteration 0 (issues before staging loads) ----
    float4 qf[4];
    {
        const int m0 = mg * MPG;
        const float* qp = Q + ((size_t)b * TSEQ + (m0 << 6) + r) * EDIM;
        qf[0] = *(const float4*)(qp + kq);
        qf[1] = *(const float4*)(qp + kq + 4);
        qf[2] = *(const float4*)(qp + 32 + kq);
        qf[3] = *(const float4*)(qp + 32 + kq + 4);
    }

    // ---- stage Kc (bf16) and VcT (bf16, transposed) ONCE per workgroup ----
    {
        const int j = tid >> 1;                // column 0..127
        const int h = (tid & 1) << 5;          // dim half: 0 or 32
        const size_t src = ((size_t)b * TSEQ + (j * 64 + 63)) * EDIM + h;
        const float4* ks = (const float4*)(K + src);
        const float4* vs = (const float4*)(V + src);
        #pragma unroll
        for (int t = 0; t < 8; ++t) {
            float4 kf = ks[t];
            unsigned int p0 = (unsigned int)f2bf(kf.x) | ((unsigned int)f2bf(kf.y) << 16);
            unsigned int p1 = (unsigned int)f2bf(kf.z) | ((unsigned int)f2bf(kf.w) << 16);
            *(unsigned int*)&Kc[j][h + 4 * t]     = p0;
            *(unsigned int*)&Kc[j][h + 4 * t + 2] = p1;
        }
        #pragma unroll
        for (int t = 0; t < 8; ++t) {
            float4 vf = vs[t];
            VcT[h + 4 * t + 0][j] = f2bf(vf.x);
            VcT[h + 4 * t + 1][j] = f2bf(vf.y);
            VcT[h + 4 * t + 2][j] = f2bf(vf.z);
            VcT[h + 4 * t + 3][j] = f2bf(vf.w);
        }
    }
    __syncthreads();                           // staging visible (the ONLY barrier)

    for (int it = 0; it < MPG; ++it) {
        const int m = mg * MPG + it;
        const size_t rowbase = (size_t)b * TSEQ + ((size_t)m << 6);

        // ---- convert prefetched Q (pre-scaled by 1/8) ----
        short8 qa[2];
        #pragma unroll
        for (int s = 0; s < 2; ++s) {
            float4 f0 = qf[2 * s], f1 = qf[2 * s + 1];
            short8 v;
            v[0] = (short)f2bf(f0.x * 0.125f); v[1] = (short)f2bf(f0.y * 0.125f);
            v[2] = (short)f2bf(f0.z * 0.125f); v[3] = (short)f2bf(f0.w * 0.125f);
            v[4] = (short)f2bf(f1.x * 0.125f); v[5] = (short)f2bf(f1.y * 0.125f);
            v[6] = (short)f2bf(f1.z * 0.125f); v[7] = (short)f2bf(f1.w * 0.125f);
            qa[s] = v;
        }

        // ---- GEMM1 (swapped): acc[t] = Z^T tile (col-tile t, row-block wid)
        //      lane holds Z[row=r][col=16t+cb+reg] for reg=0..3
        f32x4 acc[8];
        #pragma unroll
        for (int t = 0; t < 8; ++t) acc[t] = (f32x4)0.f;
        #pragma unroll
        for (int t = 0; t < 8; ++t) {
            const unsigned short* kr = &Kc[(t << 4) + c][0];
            short8 b0 = *(const short8*)(kr + kq);
            short8 b1 = *(const short8*)(kr + 32 + kq);
            acc[t] = __builtin_amdgcn_mfma_f32_16x16x32_bf16(b0, qa[0], acc[t], 0, 0, 0);
            acc[t] = __builtin_amdgcn_mfma_f32_16x16x32_bf16(b1, qa[1], acc[t], 0, 0, 0);
        }

        // ---- prefetch Q for next iteration ----
        if (it + 1 < MPG) {
            const float* qp = Q + (rowbase + 64 + r) * EDIM;
            qf[0] = *(const float4*)(qp + kq);
            qf[1] = *(const float4*)(qp + kq + 4);
            qf[2] = *(const float4*)(qp + 32 + kq);
            qf[3] = *(const float4*)(qp + 32 + kq + 4);
        }

        // ---- mask + exp + per-lane row sum (row is lane-local!) ----
        const int nv = m + (r == 63 ? 1 : 0);
        float sum = 0.f;
        #pragma unroll
        for (int t = 0; t < 8; ++t) {
            const int j0 = (t << 4) + cb;
            #pragma unroll
            for (int reg = 0; reg < 4; ++reg) {
                float e = (j0 + reg < nv) ? __expf(acc[t][reg]) : 0.f;
                acc[t][reg] = e;
                sum += e;
            }
        }
        sum += __shfl_xor(sum, 16);            // combine the 4 col sub-blocks
        sum += __shfl_xor(sum, 32);
        const float rinv = (sum > 0.f) ? 1.0f / sum : 0.f;
        #pragma unroll
        for (int t = 0; t < 8; ++t) {
            acc[t][0] *= rinv; acc[t][1] *= rinv;
            acc[t][2] *= rinv; acc[t][3] *= rinv;
        }

        // ---- A output: 8 x float4 (4 contiguous cols per lane per tile) ----
        {
            float* ap = A + (rowbase + r) * NCOL + cb;
            #pragma unroll
            for (int t = 0; t < 8; ++t)
                *(f32x4*)(ap + (t << 4)) = acc[t];
        }

        // ---- Aw (bf16) -> LDS, wave-private stripe, 8 x b64 writes ----
        asm volatile("" ::: "memory");   // order after prev iter's Aw reads
        #pragma unroll
        for (int t = 0; t < 8; ++t) {
            short4v w;
            w[0] = (short)f2bf(acc[t][0]); w[1] = (short)f2bf(acc[t][1]);
            w[2] = (short)f2bf(acc[t][2]); w[3] = (short)f2bf(acc[t][3]);
            *(short4v*)&Aw[r][(t << 4) + cb] = w;
        }
        // wave-local fence replaces both __syncthreads: producer == consumer wave
        asm volatile("s_waitcnt lgkmcnt(0)" ::: "memory");

        // ---- GEMM2 (swapped): oacc[te] = out^T tile (te, wid) ----
        short8 af[4];
        {
            const unsigned short* ar = &Aw[r][0];
            #pragma unroll
            for (int s = 0; s < 4; ++s)
                af[s] = *(const short8*)(ar + (s << 5) + kq);
        }
        f32x4 oacc[4];
        #pragma unroll
        for (int te = 0; te < 4; ++te) oacc[te] = (f32x4)0.f;
        #pragma unroll
        for (int te = 0; te < 4; ++te) {
            const unsigned short* vr = &VcT[(te << 4) + c][0];
            #pragma unroll
            for (int s = 0; s < 4; ++s) {
                short8 va = *(const short8*)(vr + (s << 5) + kq);
                oacc[te] = __builtin_amdgcn_mfma_f32_16x16x32_bf16(va, af[s], oacc[te], 0, 0, 0);
            }
        }

        // ---- Out: 4 x float4 (4 contiguous e-dims per lane per tile) ----
        {
            float* op = Out + (rowbase + r) * EDIM + cb;
            #pragma unroll
            for (int te = 0; te < 4; ++te)
                *(f32x4*)(op + (te << 4)) = oacc[te];
        }
    }
}

extern "C" void kernel_launch(void* const* d_in, const int* in_sizes, int n_in,
                              void* d_out, int out_size, void* d_ws, size_t ws_size,
                              hipStream_t stream) {
    const float* Q = (const float*)d_in[0];
    const float* K = (const float*)d_in[1];
    const float* V = (const float*)d_in[2];
    float* Out = (float*)d_out;
    float* A   = Out + (size_t)NBATCH * TSEQ * EDIM;

    // 512 workgroups x 256 threads: one per (batch, 4 m-blocks); ~2 wgs/CU
    cba_kernel<<<dim3(NBATCH * 32), dim3(256), 0, stream>>>(Q, K, V, Out, A);
}